// Round 4
// baseline (2901.714 us; speedup 1.0000x reference)
//
#include <hip/hip_runtime.h>

// Persistent-kernel LSTM autoencoder.
// enc/dec run as ONE kernel each: 256 blocks (1/CU), 8 independent groups of
// 32 blocks (group = 64-batch slice); per-step sync via device-scope atomic
// counter among the 32 group blocks only. Weights live in LDS; c in registers;
// h exchanged through agent-coherent loads/stores. z = one big GEMM at end.

#define Bsz 512
#define Tsz 128
#define Esz 256
#define Hsz 512
#define Zsz 256
#define NG  2048   // 4*Hsz gate columns (interleaved n = 4*j + gate)

typedef _Float16 f16;
typedef unsigned long long ull;
typedef __attribute__((ext_vector_type(8))) _Float16 f16x8;
typedef __attribute__((ext_vector_type(4))) float f32x4;

__device__ __forceinline__ float sigm(float x) { return 1.0f / (1.0f + __expf(-x)); }

// column swizzle within 64-col k-tiles (bits 3..5 XOR row&7) — involution
__device__ __forceinline__ int swz(int kd, int r) {
    return (kd & ~56) | ((((kd >> 3) & 7) ^ (r & 7)) << 3);
}

__device__ __forceinline__ void gld16(const void* g, void* l) {
    __builtin_amdgcn_global_load_lds(
        (const __attribute__((address_space(1))) unsigned*)g,
        (__attribute__((address_space(3))) unsigned*)l, 16, 0, 0);
}

__device__ __forceinline__ ull ld_agent(const ull* p) {
    return __hip_atomic_load(p, __ATOMIC_RELAXED, __HIP_MEMORY_SCOPE_AGENT);
}
__device__ __forceinline__ void st_h16(f16* p, float v) {
    f16 h = (f16)v;
    unsigned short u;
    __builtin_memcpy(&u, &h, 2);
    __hip_atomic_store((unsigned short*)p, u, __ATOMIC_RELAXED, __HIP_MEMORY_SCOPE_AGENT);
}

// ---------------------------------------------------------------------------
// prep: x -> fp16 swizzled [B][T][E]; weights -> fp16 gate-interleaved +
// swizzled; bias folding; h0 init; zero barrier counters.
// ---------------------------------------------------------------------------
__global__ __launch_bounds__(256) void prep_kernel(
    const float* __restrict__ x,
    const float* __restrict__ enc_W_ih, const float* __restrict__ enc_W_hh,
    const float* __restrict__ enc_b_ih, const float* __restrict__ enc_b_hh,
    const float* __restrict__ dec_W_ih, const float* __restrict__ dec_W_hh,
    const float* __restrict__ dec_b_ih, const float* __restrict__ dec_b_hh,
    const float* __restrict__ z_W,
    f16* __restrict__ x16,   f16* __restrict__ eih_s, f16* __restrict__ ehh_s,
    f16* __restrict__ dhh_s, f16* __restrict__ wsm_s, f16* __restrict__ zw_s,
    float* __restrict__ encB, float* __restrict__ decB, float* __restrict__ decB0,
    f16* __restrict__ hb0, unsigned* __restrict__ ctrbuf)
{
    const int tid = blockIdx.x * 256 + threadIdx.x;   // 512 blocks -> 131072 thr
    const int NT  = 512 * 256;

    if (blockIdx.x == 0 && threadIdx.x < 256) ctrbuf[threadIdx.x] = 0;

    for (int i = tid; i < Bsz * Hsz; i += NT) hb0[i] = (f16)0.1f;

    // x16[b][t][kd] = x[b][t][swz(kd,b)]
    for (int i = tid; i < Bsz * Tsz * Esz; i += NT) {
        const int b = i >> 15, r = i & 32767, t = r >> 8, kd = r & 255;
        x16[i] = (f16)x[(size_t)b * 32768 + t * 256 + swz(kd, b)];
    }
    // enc W_ih: [NG][E]
    for (int i = tid; i < NG * Esz; i += NT) {
        const int n = i >> 8, kd = i & 255;
        const int sr = (n & 3) * Hsz + (n >> 2);
        eih_s[i] = (f16)enc_W_ih[sr * Esz + swz(kd, n)];
    }
    // enc W_hh, dec W_hh, Wsum: [NG][H]
    for (int i = tid; i < NG * Hsz; i += NT) {
        const int n = i >> 9, kd = i & 511;
        const int sr = (n & 3) * Hsz + (n >> 2);
        const int ks = swz(kd, n);
        ehh_s[i] = (f16)enc_W_hh[sr * Hsz + ks];
        const float dv = dec_W_hh[sr * Hsz + ks];
        dhh_s[i] = (f16)dv;
        wsm_s[i] = (f16)(dec_W_ih[sr * Hsz + ks] + dv);
    }
    // z_W: [Z][H]
    for (int i = tid; i < Zsz * Hsz; i += NT) {
        const int n = i >> 9, kd = i & 511;
        zw_s[i] = (f16)z_W[n * Hsz + swz(kd, n)];
    }

    const int wave = tid >> 6, lane = tid & 63;   // 2048 waves exactly
    if (wave < NG) {
        const int sr = (wave & 3) * Hsz + (wave >> 2);
        float s = 0.f;
        for (int k = lane; k < Hsz; k += 64) s += dec_W_ih[sr * Hsz + k];
        for (int off = 32; off; off >>= 1) s += __shfl_down(s, off);
        if (lane == 0) {
            encB[wave] = enc_b_ih[sr] + enc_b_hh[sr];
            const float bi = dec_b_ih[sr] + dec_b_hh[sr];
            decB[wave]  = bi;
            decB0[wave] = bi + 0.1f * s;
        }
    }
}

// ---------------------------------------------------------------------------
// Persistent LSTM phase. 256 blocks, group g = bid&7 owns batch slice
// [g*64, g*64+64); ny = bid>>3 owns gate cols [ny*64, ny*64+64).
// ---------------------------------------------------------------------------
template <bool ENC>
__global__ __launch_bounds__(256, 1) void persist_kernel(
    const f16* __restrict__ x16,     // [B][T][E]      (ENC)
    const f16* __restrict__ Wih_g,   // eih_s          (ENC)
    const f16* __restrict__ Whh_g,   // ehh_s / dhh_s
    const f16* __restrict__ Wsm_g,   // wsm_s          (DEC)
    const float* __restrict__ biasA, // encB / decB
    const float* __restrict__ biasB, // decB0          (DEC)
    f16* __restrict__ hb0, f16* __restrict__ hb1,
    float* __restrict__ cbuf,        // [B][H] c handoff
    f16* __restrict__ Hall,          // [B*T][H]       (DEC)
    unsigned* __restrict__ ctr)      // 8 slots, 64B apart
{
    __shared__ f16 Wih[ENC ? 4 * 4096 : 8];   // [kt][64][64] tiles
    __shared__ f16 Whh[8 * 4096];
    __shared__ f16 As[2][4096];
    __shared__ float gbuf[64][65];

    const int tid = threadIdx.x;
    const int bid = blockIdx.x;
    const int bx = bid & 7, ny = bid >> 3;
    const int b0 = bx * 64, n0 = ny * 64, j0 = ny * 16;
    const int lane = tid & 63, w = tid >> 6;
    const int lr = lane & 15, lkb = lane >> 4;
    const int wm = (w & 1) * 32, wn = (w >> 1) * 32;
    const int rl = lane >> 3, kc = (lane & 7) * 8;  // W-load lane pattern
    const int r0 = tid >> 3, koff = (tid & 7) * 8;  // A-load: rows r0, r0+32
    const int ty = tid >> 4, tx = tid & 15;         // epilogue mapping

    constexpr int KT = ENC ? 12 : 8;
    constexpr int XO = ENC ? 4 : 0;

    // ---- load resident weights into LDS ----
#pragma unroll
    for (int kt = 0; kt < 8; ++kt)
#pragma unroll
        for (int s = 0; s < 2; ++s) {
            const int g = w + s * 4, row = g * 8 + rl;
            gld16(Whh_g + (size_t)(n0 + row) * Hsz + kt * 64 + kc, &Whh[kt * 4096 + g * 512]);
        }
    if (ENC) {
#pragma unroll
        for (int kt = 0; kt < 4; ++kt)
#pragma unroll
            for (int s = 0; s < 2; ++s) {
                const int g = w + s * 4, row = g * 8 + rl;
                gld16(Wih_g + (size_t)(n0 + row) * Esz + kt * 64 + kc, &Wih[kt * 4096 + g * 512]);
            }
    }
    __syncthreads();

    // ---- persistent state ----
    float bvA[2], bvB[2];
#pragma unroll
    for (int j = 0; j < 2; ++j) {
        bvA[j] = biasA[n0 + wn + j * 16 + lr];
        bvB[j] = ENC ? 0.f : biasB[n0 + wn + j * 16 + lr];
    }
    float c_reg[4];
#pragma unroll
    for (int rep = 0; rep < 4; ++rep)
        c_reg[rep] = ENC ? 0.1f : cbuf[(size_t)(b0 + rep * 16 + ty) * Hsz + j0 + tx];

    unsigned* myctr = &ctr[bx * 16];

    for (int t = 0; t < Tsz; ++t) {
        // ---- wait for previous step's h ----
        if (t > 0) {
            if (tid == 0) {
                const unsigned tgt = 32u * (unsigned)t;
                while (__hip_atomic_load(myctr, __ATOMIC_RELAXED, __HIP_MEMORY_SCOPE_AGENT) < tgt)
                    __builtin_amdgcn_s_sleep(1);
                (void)__hip_atomic_load(myctr, __ATOMIC_ACQUIRE, __HIP_MEMORY_SCOPE_AGENT);
            }
            __syncthreads();
        }

        const f16* hsrc = (t & 1) ? hb1 : hb0;
        f16*       hdst = (t & 1) ? hb0 : hb1;

        // ---- issue ALL of this step's A loads ----
        ull areg[KT][4];
        if (ENC) {
#pragma unroll
            for (int kt = 0; kt < 4; ++kt) {
                const ull* p0 = (const ull*)(x16 + ((size_t)(b0 + r0) * Tsz + t) * Esz + kt * 64 + koff);
                const ull* p1 = (const ull*)(x16 + ((size_t)(b0 + r0 + 32) * Tsz + t) * Esz + kt * 64 + koff);
                areg[kt][0] = p0[0]; areg[kt][1] = p0[1];
                areg[kt][2] = p1[0]; areg[kt][3] = p1[1];
            }
        }
#pragma unroll
        for (int kt = 0; kt < KT - XO; ++kt) {
            const ull* p0 = (const ull*)(hsrc + (size_t)(b0 + r0) * Hsz + kt * 64 + koff);
            const ull* p1 = (const ull*)(hsrc + (size_t)(b0 + r0 + 32) * Hsz + kt * 64 + koff);
            areg[XO + kt][0] = ld_agent(p0);     areg[XO + kt][1] = ld_agent(p0 + 1);
            areg[XO + kt][2] = ld_agent(p1);     areg[XO + kt][3] = ld_agent(p1 + 1);
        }

        // ---- accumulators ----
        f32x4 acc[2][2];
#pragma unroll
        for (int j = 0; j < 2; ++j) {
            const float bv = (!ENC && t == 0) ? bvB[j] : bvA[j];
            acc[0][j] = (f32x4){bv, bv, bv, bv};
            acc[1][j] = acc[0][j];
        }

        // ---- K loop ----
#pragma unroll
        for (int kt = 0; kt < KT; ++kt) {
            *(ull*)&As[kt & 1][r0 * 64 + koff]            = areg[kt][0];
            *(ull*)&As[kt & 1][r0 * 64 + koff + 4]        = areg[kt][1];
            *(ull*)&As[kt & 1][(r0 + 32) * 64 + koff]     = areg[kt][2];
            *(ull*)&As[kt & 1][(r0 + 32) * 64 + koff + 4] = areg[kt][3];
            __syncthreads();

            const f16* Acur = &As[kt & 1][0];
            const f16* Bt = (ENC && kt < 4) ? &Wih[kt * 4096]
                                            : &Whh[(ENC ? kt - 4 : kt) * 4096];
            f16x8 af[2][2], bf[2][2];
#pragma unroll
            for (int i = 0; i < 2; ++i) {
                const int ra = wm + i * 16 + lr;
                const int rb = wn + i * 16 + lr;
#pragma unroll
                for (int ks = 0; ks < 2; ++ks) {
                    af[i][ks] = *(const f16x8*)&Acur[ra * 64 + (((ks * 4 + lkb) ^ (ra & 7)) * 8)];
                    bf[i][ks] = *(const f16x8*)&Bt[rb * 64 + (((ks * 4 + lkb) ^ (rb & 7)) * 8)];
                }
            }
#pragma unroll
            for (int ks = 0; ks < 2; ++ks)
#pragma unroll
                for (int i = 0; i < 2; ++i)
#pragma unroll
                    for (int j = 0; j < 2; ++j)
                        acc[i][j] = __builtin_amdgcn_mfma_f32_16x16x32_f16(
                            af[i][ks], bf[j][ks], acc[i][j], 0, 0, 0);
        }

        // ---- epilogue: gate exchange + LSTM elementwise ----
#pragma unroll
        for (int i = 0; i < 2; ++i)
#pragma unroll
            for (int j = 0; j < 2; ++j)
#pragma unroll
                for (int r = 0; r < 4; ++r)
                    gbuf[wn + j * 16 + lr][wm + i * 16 + lkb * 4 + r] = acc[i][j][r];
        __syncthreads();

#pragma unroll
        for (int rep = 0; rep < 4; ++rep) {
            const int m = rep * 16 + ty, jj = tx;
            const float gi = gbuf[4 * jj + 0][m];
            const float gf = gbuf[4 * jj + 1][m];
            const float gg = gbuf[4 * jj + 2][m];
            const float go = gbuf[4 * jj + 3][m];
            const float iv = sigm(gi), fv = sigm(gf);
            const float gv = tanhf(gg), ov = sigm(go);
            const float cn = fv * c_reg[rep] + iv * gv;
            c_reg[rep] = cn;
            const float hv = ov * tanhf(cn);
            const int bq = b0 + m, col = j0 + jj;
            st_h16(&hdst[(size_t)bq * Hsz + swz(col, bq)], hv);
            if (!ENC)
                Hall[((size_t)bq * Tsz + t) * Hsz + swz(col, t)] = (f16)hv;
        }

        // ---- signal this step done ----
        if (t < Tsz - 1) {
            __syncthreads();   // all h stores drained (barrier drains vmcnt)
            if (tid == 0)
                __hip_atomic_fetch_add(myctr, 1u, __ATOMIC_RELEASE, __HIP_MEMORY_SCOPE_AGENT);
        }

        // ---- decoder: swap LDS weights dhh -> Wsum after step 0 ----
        if (!ENC && t == 0) {
#pragma unroll
            for (int kt = 0; kt < 8; ++kt)
#pragma unroll
                for (int s = 0; s < 2; ++s) {
                    const int g = w + s * 4, row = g * 8 + rl;
                    gld16(Wsm_g + (size_t)(n0 + row) * Hsz + kt * 64 + kc, &Whh[kt * 4096 + g * 512]);
                }
            __syncthreads();
        }
    }

    if (ENC) {
#pragma unroll
        for (int rep = 0; rep < 4; ++rep)
            cbuf[(size_t)(b0 + rep * 16 + ty) * Hsz + j0 + tx] = c_reg[rep];
    }
}

// ---------------------------------------------------------------------------
// final z projection: out[m][col] = tanh(Hall[m] @ zW^T + zb), m = b*T + t
// grid (1024, 4), 64x64 tiles
// ---------------------------------------------------------------------------
__global__ __launch_bounds__(256, 2) void z_final(
    const f16* __restrict__ Hall, const f16* __restrict__ zw,
    const float* __restrict__ zb, float* __restrict__ out)
{
    __shared__ f16 As[2][4096];
    __shared__ f16 Bs[2][4096];

    const int tid = threadIdx.x;
    const int lane = tid & 63, w = tid >> 6;
    const int lr = lane & 15, lkb = lane >> 4;
    const int wm = (w & 1) * 32, wn = (w >> 1) * 32;
    const int m0 = blockIdx.x * 64;
    const int n0 = blockIdx.y * 64;
    const int rl = lane >> 3, kc = (lane & 7) * 8;

    f32x4 acc[2][2];
#pragma unroll
    for (int j = 0; j < 2; ++j) {
        const float bv = zb[n0 + wn + j * 16 + lr];
        acc[0][j] = (f32x4){bv, bv, bv, bv};
        acc[1][j] = acc[0][j];
    }

    auto stage = [&](int buf, int kt) {
#pragma unroll
        for (int s = 0; s < 2; ++s) {
            const int g = w + s * 4, row = g * 8 + rl;
            gld16(Hall + (size_t)(m0 + row) * Hsz + kt * 64 + kc, &As[buf][g * 512]);
            gld16(zw   + (size_t)(n0 + row) * Hsz + kt * 64 + kc, &Bs[buf][g * 512]);
        }
    };

    stage(0, 0);
    int cur = 0;
    for (int kt = 0; kt < 8; ++kt) {
        asm volatile("s_waitcnt vmcnt(0)" ::: "memory");
        __syncthreads();
        if (kt + 1 < 8) stage(cur ^ 1, kt + 1);
        f16x8 af[2][2], bf[2][2];
#pragma unroll
        for (int i = 0; i < 2; ++i) {
            const int ra = wm + i * 16 + lr;
            const int rb = wn + i * 16 + lr;
#pragma unroll
            for (int ks = 0; ks < 2; ++ks) {
                af[i][ks] = *(const f16x8*)&As[cur][ra * 64 + (((ks * 4 + lkb) ^ (ra & 7)) * 8)];
                bf[i][ks] = *(const f16x8*)&Bs[cur][rb * 64 + (((ks * 4 + lkb) ^ (rb & 7)) * 8)];
            }
        }
#pragma unroll
        for (int ks = 0; ks < 2; ++ks)
#pragma unroll
            for (int i = 0; i < 2; ++i)
#pragma unroll
                for (int j = 0; j < 2; ++j)
                    acc[i][j] = __builtin_amdgcn_mfma_f32_16x16x32_f16(
                        af[i][ks], bf[j][ks], acc[i][j], 0, 0, 0);
        cur ^= 1;
    }
#pragma unroll
    for (int i = 0; i < 2; ++i)
#pragma unroll
        for (int j = 0; j < 2; ++j)
#pragma unroll
            for (int r = 0; r < 4; ++r) {
                const int m = m0 + wm + i * 16 + lkb * 4 + r;
                const int col = n0 + wn + j * 16 + lr;
                out[(size_t)m * Zsz + col] = tanhf(acc[i][j][r]);
            }
}

// ---------------------------------------------------------------------------
extern "C" void kernel_launch(void* const* d_in, const int* in_sizes, int n_in,
                              void* d_out, int out_size, void* d_ws, size_t ws_size,
                              hipStream_t stream) {
    (void)in_sizes; (void)n_in; (void)out_size; (void)ws_size;
    const float* x        = (const float*)d_in[0];
    const float* enc_W_ih = (const float*)d_in[1];
    const float* enc_W_hh = (const float*)d_in[2];
    const float* enc_b_ih = (const float*)d_in[3];
    const float* enc_b_hh = (const float*)d_in[4];
    const float* dec_W_ih = (const float*)d_in[5];
    const float* dec_W_hh = (const float*)d_in[6];
    const float* dec_b_ih = (const float*)d_in[7];
    const float* dec_b_hh = (const float*)d_in[8];
    const float* z_W      = (const float*)d_in[9];
    const float* z_b      = (const float*)d_in[10];
    float* out = (float*)d_out;

    // workspace layout
    unsigned* ctrbuf = (unsigned*)d_ws;              // 256 u32 (enc: 0..127, dec: 128..255)
    float* fp   = (float*)(ctrbuf + 256);
    float* encB  = fp;  fp += NG;
    float* decB  = fp;  fp += NG;
    float* decB0 = fp;  fp += NG;
    float* cbuf  = fp;  fp += Bsz * Hsz;
    f16* hp    = (f16*)fp;
    f16* hb0   = hp;  hp += Bsz * Hsz;
    f16* hb1   = hp;  hp += Bsz * Hsz;
    f16* x16   = hp;  hp += (size_t)Bsz * Tsz * Esz;
    f16* eih_s = hp;  hp += (size_t)NG * Esz;
    f16* ehh_s = hp;  hp += (size_t)NG * Hsz;
    f16* dhh_s = hp;  hp += (size_t)NG * Hsz;
    f16* wsm_s = hp;  hp += (size_t)NG * Hsz;
    f16* zw_s  = hp;  hp += (size_t)Zsz * Hsz;
    f16* Hall  = hp;  hp += (size_t)Bsz * Tsz * Hsz;

    prep_kernel<<<512, 256, 0, stream>>>(
        x, enc_W_ih, enc_W_hh, enc_b_ih, enc_b_hh,
        dec_W_ih, dec_W_hh, dec_b_ih, dec_b_hh, z_W,
        x16, eih_s, ehh_s, dhh_s, wsm_s, zw_s,
        encB, decB, decB0, hb0, ctrbuf);

    persist_kernel<true><<<256, 256, 0, stream>>>(
        x16, eih_s, ehh_s, nullptr, encB, nullptr,
        hb0, hb1, cbuf, nullptr, ctrbuf);

    persist_kernel<false><<<256, 256, 0, stream>>>(
        nullptr, nullptr, dhh_s, wsm_s, decB, decB0,
        hb0, hb1, cbuf, Hall, ctrbuf + 128);

    z_final<<<dim3(1024, 4), 256, 0, stream>>>(Hall, zw_s, z_b, out);
}

// Round 5
// 2410.459 us; speedup vs baseline: 1.2038x; 1.2038x over previous
//
#include <hip/hip_runtime.h>

// Persistent-kernel LSTM autoencoder, round 5.
// - per-producer flag barrier (no atomic-RMW serialization)
// - h-part weights resident in REGISTERS (B-frags), x-part in LDS (enc)
// - packed 8B h exchange stores

#define Bsz 512
#define Tsz 128
#define Esz 256
#define Hsz 512
#define Zsz 256
#define NG  2048   // 4*Hsz gate columns (interleaved n = 4*j + gate)

typedef _Float16 f16;
typedef unsigned long long ull;
typedef __attribute__((ext_vector_type(8))) _Float16 f16x8;
typedef __attribute__((ext_vector_type(4))) float f32x4;

__device__ __forceinline__ float sigm(float x) { return 1.0f / (1.0f + __expf(-x)); }

// column swizzle within 64-col k-tiles (bits 3..5 XOR row&7) — involution
__device__ __forceinline__ int swz(int kd, int r) {
    return (kd & ~56) | ((((kd >> 3) & 7) ^ (r & 7)) << 3);
}

__device__ __forceinline__ void gld16(const void* g, void* l) {
    __builtin_amdgcn_global_load_lds(
        (const __attribute__((address_space(1))) unsigned*)g,
        (__attribute__((address_space(3))) unsigned*)l, 16, 0, 0);
}

__device__ __forceinline__ ull ld_agent(const ull* p) {
    return __hip_atomic_load(p, __ATOMIC_RELAXED, __HIP_MEMORY_SCOPE_AGENT);
}

// ---------------------------------------------------------------------------
// prep: x -> fp16 swizzled; weights -> fp16 gate-interleaved + swizzled;
// bias folding; h0 init; zero flag arrays.
// ---------------------------------------------------------------------------
__global__ __launch_bounds__(256) void prep_kernel(
    const float* __restrict__ x,
    const float* __restrict__ enc_W_ih, const float* __restrict__ enc_W_hh,
    const float* __restrict__ enc_b_ih, const float* __restrict__ enc_b_hh,
    const float* __restrict__ dec_W_ih, const float* __restrict__ dec_W_hh,
    const float* __restrict__ dec_b_ih, const float* __restrict__ dec_b_hh,
    const float* __restrict__ z_W,
    f16* __restrict__ x16,   f16* __restrict__ eih_s, f16* __restrict__ ehh_s,
    f16* __restrict__ dhh_s, f16* __restrict__ wsm_s, f16* __restrict__ zw_s,
    float* __restrict__ encB, float* __restrict__ decB, float* __restrict__ decB0,
    f16* __restrict__ hb0, unsigned* __restrict__ flags)
{
    const int tid = blockIdx.x * 256 + threadIdx.x;   // 512 blocks -> 131072 thr
    const int NT  = 512 * 256;

    if (tid < 8192) flags[tid] = 0;   // enc 0..4095, dec 4096..8191

    for (int i = tid; i < Bsz * Hsz; i += NT) hb0[i] = (f16)0.1f;

    // x16[b][t][kd] = x[b][t][swz(kd,b)]
    for (int i = tid; i < Bsz * Tsz * Esz; i += NT) {
        const int b = i >> 15, r = i & 32767, t = r >> 8, kd = r & 255;
        x16[i] = (f16)x[(size_t)b * 32768 + t * 256 + swz(kd, b)];
    }
    // enc W_ih: [NG][E]
    for (int i = tid; i < NG * Esz; i += NT) {
        const int n = i >> 8, kd = i & 255;
        const int sr = (n & 3) * Hsz + (n >> 2);
        eih_s[i] = (f16)enc_W_ih[sr * Esz + swz(kd, n)];
    }
    // enc W_hh, dec W_hh, Wsum: [NG][H]
    for (int i = tid; i < NG * Hsz; i += NT) {
        const int n = i >> 9, kd = i & 511;
        const int sr = (n & 3) * Hsz + (n >> 2);
        const int ks = swz(kd, n);
        ehh_s[i] = (f16)enc_W_hh[sr * Hsz + ks];
        const float dv = dec_W_hh[sr * Hsz + ks];
        dhh_s[i] = (f16)dv;
        wsm_s[i] = (f16)(dec_W_ih[sr * Hsz + ks] + dv);
    }
    // z_W: [Z][H]
    for (int i = tid; i < Zsz * Hsz; i += NT) {
        const int n = i >> 9, kd = i & 511;
        zw_s[i] = (f16)z_W[n * Hsz + swz(kd, n)];
    }

    const int wave = tid >> 6, lane = tid & 63;   // 2048 waves exactly
    if (wave < NG) {
        const int sr = (wave & 3) * Hsz + (wave >> 2);
        float s = 0.f;
        for (int k = lane; k < Hsz; k += 64) s += dec_W_ih[sr * Hsz + k];
        for (int off = 32; off; off >>= 1) s += __shfl_down(s, off);
        if (lane == 0) {
            encB[wave] = enc_b_ih[sr] + enc_b_hh[sr];
            const float bi = dec_b_ih[sr] + dec_b_hh[sr];
            decB[wave]  = bi;
            decB0[wave] = bi + 0.1f * s;
        }
    }
}

// ---------------------------------------------------------------------------
// Persistent LSTM phase. 256 blocks; group bx = bid&7 owns batch rows
// [bx*64, +64); ny = bid>>3 owns gate cols [ny*64, +64).
// Step sync: per-producer flags (64B apart), consumer polls 32 in parallel.
// ---------------------------------------------------------------------------
template <bool ENC>
__global__ __launch_bounds__(256, 1) void persist_kernel(
    const f16* __restrict__ x16,     // [B][T][E]      (ENC)
    const f16* __restrict__ Wih_g,   // eih_s          (ENC)
    const f16* __restrict__ Whh_g,   // ehh_s / dhh_s
    const f16* __restrict__ Wsm_g,   // wsm_s          (DEC)
    const float* __restrict__ biasA, // encB / decB
    const float* __restrict__ biasB, // decB0          (DEC)
    f16* __restrict__ hb0, f16* __restrict__ hb1,
    float* __restrict__ cbuf,        // [B][H] c handoff
    f16* __restrict__ Hall,          // [B*T][H]       (DEC)
    unsigned* __restrict__ flags)    // [8 groups][32 producers][16]
{
    __shared__ f16 Wih[4 * 4096];      // enc x-weights (dec: kept for LDS sizing)
    __shared__ f16 As[2][4096];
    __shared__ float gbuf[64][129];    // >80KB total -> forced 1 block/CU

    const int tid = threadIdx.x;
    const int bid = blockIdx.x;
    const int bx = bid & 7, ny = bid >> 3;
    const int b0 = bx * 64, n0 = ny * 64, j0 = ny * 16;
    const int lane = tid & 63, w = tid >> 6;
    const int lr = lane & 15, lkb = lane >> 4;
    const int wm = (w & 1) * 32, wn = (w >> 1) * 32;
    const int rl = lane >> 3, kc = (lane & 7) * 8;  // gld16 lane pattern
    const int r0 = tid >> 3, koff = (tid & 7) * 8;  // A-load rows r0, r0+32
    const int em = tid >> 2, ec = (tid & 3) * 4;    // epilogue: row em, cols ec..ec+3

    constexpr int KT = ENC ? 12 : 8;
    constexpr int XO = ENC ? 4 : 0;

    // keep Wih allocation alive in DEC without touching it (blockDim is opaque)
    if (!ENC && blockDim.x > 1024) Wih[0] = (f16)0;

    // ---- h-part weight fragments -> registers (step-invariant) ----
    f16x8 bfr[8][2][2];
#pragma unroll
    for (int kt = 0; kt < 8; ++kt)
#pragma unroll
        for (int j = 0; j < 2; ++j) {
            const int rb = wn + j * 16 + lr;
#pragma unroll
            for (int ks = 0; ks < 2; ++ks)
                bfr[kt][j][ks] = *(const f16x8*)&Whh_g[
                    (size_t)(n0 + rb) * Hsz + kt * 64 + (((ks * 4 + lkb) ^ (rb & 7)) * 8)];
        }
    if (ENC) {
#pragma unroll
        for (int kt = 0; kt < 4; ++kt)
#pragma unroll
            for (int s = 0; s < 2; ++s) {
                const int g = w + s * 4, row = g * 8 + rl;
                gld16(Wih_g + (size_t)(n0 + row) * Esz + kt * 64 + kc, &Wih[kt * 4096 + g * 512]);
            }
    }

    float bvA[2], bvB[2];
#pragma unroll
    for (int j = 0; j < 2; ++j) {
        bvA[j] = biasA[n0 + wn + j * 16 + lr];
        bvB[j] = ENC ? 0.f : biasB[n0 + wn + j * 16 + lr];
    }
    float c_reg[4];
#pragma unroll
    for (int u = 0; u < 4; ++u)
        c_reg[u] = ENC ? 0.1f : cbuf[(size_t)(b0 + em) * Hsz + j0 + ec + u];

    asm volatile("s_waitcnt vmcnt(0)" ::: "memory");
    __syncthreads();

    unsigned* gflags   = flags + bx * 512;       // 32 producers x 16 u32
    unsigned* selfflag = gflags + ny * 16;

    for (int t = 0; t < Tsz; ++t) {
        // ---- wait for previous step (parallel flag poll) ----
        if (t > 0) {
            if (tid < 32) {
                const unsigned tgt = (unsigned)t;
                const unsigned* fl = gflags + tid * 16;
                while (__hip_atomic_load(fl, __ATOMIC_RELAXED, __HIP_MEMORY_SCOPE_AGENT) < tgt)
                    __builtin_amdgcn_s_sleep(1);
                (void)__hip_atomic_load(fl, __ATOMIC_ACQUIRE, __HIP_MEMORY_SCOPE_AGENT);
            }
            __syncthreads();
        }

        const f16* hsrc = (t & 1) ? hb1 : hb0;
        f16*       hdst = (t & 1) ? hb0 : hb1;

        // ---- issue all of this step's A loads (h first: longest latency) ----
        ull areg[KT][4];
#pragma unroll
        for (int kt = 0; kt < KT - XO; ++kt) {
            const ull* p0 = (const ull*)(hsrc + (size_t)(b0 + r0) * Hsz + kt * 64 + koff);
            const ull* p1 = (const ull*)(hsrc + (size_t)(b0 + r0 + 32) * Hsz + kt * 64 + koff);
            areg[XO + kt][0] = ld_agent(p0);     areg[XO + kt][1] = ld_agent(p0 + 1);
            areg[XO + kt][2] = ld_agent(p1);     areg[XO + kt][3] = ld_agent(p1 + 1);
        }
        if (ENC) {
#pragma unroll
            for (int kt = 0; kt < 4; ++kt) {
                const ull* p0 = (const ull*)(x16 + ((size_t)(b0 + r0) * Tsz + t) * Esz + kt * 64 + koff);
                const ull* p1 = (const ull*)(x16 + ((size_t)(b0 + r0 + 32) * Tsz + t) * Esz + kt * 64 + koff);
                areg[kt][0] = p0[0]; areg[kt][1] = p0[1];
                areg[kt][2] = p1[0]; areg[kt][3] = p1[1];
            }
        }

        f32x4 acc[2][2];
#pragma unroll
        for (int j = 0; j < 2; ++j) {
            const float bv = (!ENC && t == 0) ? bvB[j] : bvA[j];
            acc[0][j] = (f32x4){bv, bv, bv, bv};
            acc[1][j] = acc[0][j];
        }

        // ---- K loop ----
#pragma unroll
        for (int kt = 0; kt < KT; ++kt) {
            *(ull*)&As[kt & 1][r0 * 64 + koff]            = areg[kt][0];
            *(ull*)&As[kt & 1][r0 * 64 + koff + 4]        = areg[kt][1];
            *(ull*)&As[kt & 1][(r0 + 32) * 64 + koff]     = areg[kt][2];
            *(ull*)&As[kt & 1][(r0 + 32) * 64 + koff + 4] = areg[kt][3];
            __syncthreads();

            f16x8 af[2][2];
#pragma unroll
            for (int i = 0; i < 2; ++i) {
                const int ra = wm + i * 16 + lr;
#pragma unroll
                for (int ks = 0; ks < 2; ++ks)
                    af[i][ks] = *(const f16x8*)&As[kt & 1][ra * 64 + (((ks * 4 + lkb) ^ (ra & 7)) * 8)];
            }
            f16x8 bq[2][2];
            if (ENC && kt < 4) {
#pragma unroll
                for (int j = 0; j < 2; ++j) {
                    const int rb = wn + j * 16 + lr;
#pragma unroll
                    for (int ks = 0; ks < 2; ++ks)
                        bq[j][ks] = *(const f16x8*)&Wih[kt * 4096 + rb * 64 + (((ks * 4 + lkb) ^ (rb & 7)) * 8)];
                }
            } else {
                const int kh = ENC ? kt - 4 : kt;
#pragma unroll
                for (int j = 0; j < 2; ++j)
#pragma unroll
                    for (int ks = 0; ks < 2; ++ks)
                        bq[j][ks] = bfr[kh][j][ks];
            }
#pragma unroll
            for (int ks = 0; ks < 2; ++ks)
#pragma unroll
                for (int i = 0; i < 2; ++i)
#pragma unroll
                    for (int j = 0; j < 2; ++j)
                        acc[i][j] = __builtin_amdgcn_mfma_f32_16x16x32_f16(
                            af[i][ks], bq[j][ks], acc[i][j], 0, 0, 0);
        }

        // ---- gate exchange + elementwise ----
#pragma unroll
        for (int i = 0; i < 2; ++i)
#pragma unroll
            for (int j = 0; j < 2; ++j)
#pragma unroll
                for (int r = 0; r < 4; ++r)
                    gbuf[wn + j * 16 + lr][wm + i * 16 + lkb * 4 + r] = acc[i][j][r];
        __syncthreads();

        f16 hp4[4];
#pragma unroll
        for (int u = 0; u < 4; ++u) {
            const int jj = ec + u;
            const float gi = gbuf[4 * jj + 0][em];
            const float gf = gbuf[4 * jj + 1][em];
            const float gg = gbuf[4 * jj + 2][em];
            const float go = gbuf[4 * jj + 3][em];
            const float iv = sigm(gi), fv = sigm(gf);
            const float gv = tanhf(gg), ov = sigm(go);
            const float cn = fv * c_reg[u] + iv * gv;
            c_reg[u] = cn;
            hp4[u] = (f16)(ov * tanhf(cn));
        }
        ull pk;
        __builtin_memcpy(&pk, hp4, 8);
        const int bq2 = b0 + em, colg = j0 + ec;
        __hip_atomic_store((ull*)&hdst[(size_t)bq2 * Hsz + swz(colg, bq2)], pk,
                           __ATOMIC_RELAXED, __HIP_MEMORY_SCOPE_AGENT);
        if (!ENC)
            *(ull*)&Hall[((size_t)bq2 * Tsz + t) * Hsz + swz(colg, t)] = pk;

        // ---- signal step done (own flag; no RMW contention) ----
        if (t < Tsz - 1) {
            asm volatile("s_waitcnt vmcnt(0)" ::: "memory");
            __syncthreads();
            if (tid == 0)
                __hip_atomic_store(selfflag, (unsigned)(t + 1),
                                   __ATOMIC_RELEASE, __HIP_MEMORY_SCOPE_AGENT);
        }

        // ---- decoder: switch register weights dhh -> Wsum after step 0 ----
        if (!ENC && t == 0) {
#pragma unroll
            for (int kt = 0; kt < 8; ++kt)
#pragma unroll
                for (int j = 0; j < 2; ++j) {
                    const int rb = wn + j * 16 + lr;
#pragma unroll
                    for (int ks = 0; ks < 2; ++ks)
                        bfr[kt][j][ks] = *(const f16x8*)&Wsm_g[
                            (size_t)(n0 + rb) * Hsz + kt * 64 + (((ks * 4 + lkb) ^ (rb & 7)) * 8)];
                }
        }
    }

    if (ENC) {
#pragma unroll
        for (int u = 0; u < 4; ++u)
            cbuf[(size_t)(b0 + em) * Hsz + j0 + ec + u] = c_reg[u];
    }
}

// ---------------------------------------------------------------------------
// final z projection: out[m][col] = tanh(Hall[m] @ zW^T + zb), m = b*T + t
// ---------------------------------------------------------------------------
__global__ __launch_bounds__(256, 2) void z_final(
    const f16* __restrict__ Hall, const f16* __restrict__ zw,
    const float* __restrict__ zb, float* __restrict__ out)
{
    __shared__ f16 As[2][4096];
    __shared__ f16 Bs[2][4096];

    const int tid = threadIdx.x;
    const int lane = tid & 63, w = tid >> 6;
    const int lr = lane & 15, lkb = lane >> 4;
    const int wm = (w & 1) * 32, wn = (w >> 1) * 32;
    const int m0 = blockIdx.x * 64;
    const int n0 = blockIdx.y * 64;
    const int rl = lane >> 3, kc = (lane & 7) * 8;

    f32x4 acc[2][2];
#pragma unroll
    for (int j = 0; j < 2; ++j) {
        const float bv = zb[n0 + wn + j * 16 + lr];
        acc[0][j] = (f32x4){bv, bv, bv, bv};
        acc[1][j] = acc[0][j];
    }

    auto stage = [&](int buf, int kt) {
#pragma unroll
        for (int s = 0; s < 2; ++s) {
            const int g = w + s * 4, row = g * 8 + rl;
            gld16(Hall + (size_t)(m0 + row) * Hsz + kt * 64 + kc, &As[buf][g * 512]);
            gld16(zw   + (size_t)(n0 + row) * Hsz + kt * 64 + kc, &Bs[buf][g * 512]);
        }
    };

    stage(0, 0);
    int cur = 0;
    for (int kt = 0; kt < 8; ++kt) {
        asm volatile("s_waitcnt vmcnt(0)" ::: "memory");
        __syncthreads();
        if (kt + 1 < 8) stage(cur ^ 1, kt + 1);
        f16x8 af[2][2], bf[2][2];
#pragma unroll
        for (int i = 0; i < 2; ++i) {
            const int ra = wm + i * 16 + lr;
            const int rb = wn + i * 16 + lr;
#pragma unroll
            for (int ks = 0; ks < 2; ++ks) {
                af[i][ks] = *(const f16x8*)&As[cur][ra * 64 + (((ks * 4 + lkb) ^ (ra & 7)) * 8)];
                bf[i][ks] = *(const f16x8*)&Bs[cur][rb * 64 + (((ks * 4 + lkb) ^ (rb & 7)) * 8)];
            }
        }
#pragma unroll
        for (int ks = 0; ks < 2; ++ks)
#pragma unroll
            for (int i = 0; i < 2; ++i)
#pragma unroll
                for (int j = 0; j < 2; ++j)
                    acc[i][j] = __builtin_amdgcn_mfma_f32_16x16x32_f16(
                        af[i][ks], bf[j][ks], acc[i][j], 0, 0, 0);
        cur ^= 1;
    }
#pragma unroll
    for (int i = 0; i < 2; ++i)
#pragma unroll
        for (int j = 0; j < 2; ++j)
#pragma unroll
            for (int r = 0; r < 4; ++r) {
                const int m = m0 + wm + i * 16 + lkb * 4 + r;
                const int col = n0 + wn + j * 16 + lr;
                out[(size_t)m * Zsz + col] = tanhf(acc[i][j][r]);
            }
}

// ---------------------------------------------------------------------------
extern "C" void kernel_launch(void* const* d_in, const int* in_sizes, int n_in,
                              void* d_out, int out_size, void* d_ws, size_t ws_size,
                              hipStream_t stream) {
    (void)in_sizes; (void)n_in; (void)out_size; (void)ws_size;
    const float* x        = (const float*)d_in[0];
    const float* enc_W_ih = (const float*)d_in[1];
    const float* enc_W_hh = (const float*)d_in[2];
    const float* enc_b_ih = (const float*)d_in[3];
    const float* enc_b_hh = (const float*)d_in[4];
    const float* dec_W_ih = (const float*)d_in[5];
    const float* dec_W_hh = (const float*)d_in[6];
    const float* dec_b_ih = (const float*)d_in[7];
    const float* dec_b_hh = (const float*)d_in[8];
    const float* z_W      = (const float*)d_in[9];
    const float* z_b      = (const float*)d_in[10];
    float* out = (float*)d_out;

    // workspace layout
    unsigned* flags = (unsigned*)d_ws;               // 8192 u32 (enc 0..4095, dec 4096..8191)
    float* fp   = (float*)(flags + 8192);
    float* encB  = fp;  fp += NG;
    float* decB  = fp;  fp += NG;
    float* decB0 = fp;  fp += NG;
    float* cbuf  = fp;  fp += Bsz * Hsz;
    f16* hp    = (f16*)fp;
    f16* hb0   = hp;  hp += Bsz * Hsz;
    f16* hb1   = hp;  hp += Bsz * Hsz;
    f16* x16   = hp;  hp += (size_t)Bsz * Tsz * Esz;
    f16* eih_s = hp;  hp += (size_t)NG * Esz;
    f16* ehh_s = hp;  hp += (size_t)NG * Hsz;
    f16* dhh_s = hp;  hp += (size_t)NG * Hsz;
    f16* wsm_s = hp;  hp += (size_t)NG * Hsz;
    f16* zw_s  = hp;  hp += (size_t)Zsz * Hsz;
    f16* Hall  = hp;  hp += (size_t)Bsz * Tsz * Hsz;

    prep_kernel<<<512, 256, 0, stream>>>(
        x, enc_W_ih, enc_W_hh, enc_b_ih, enc_b_hh,
        dec_W_ih, dec_W_hh, dec_b_ih, dec_b_hh, z_W,
        x16, eih_s, ehh_s, dhh_s, wsm_s, zw_s,
        encB, decB, decB0, hb0, flags);

    persist_kernel<true><<<256, 256, 0, stream>>>(
        x16, eih_s, ehh_s, nullptr, encB, nullptr,
        hb0, hb1, cbuf, nullptr, flags);

    persist_kernel<false><<<256, 256, 0, stream>>>(
        nullptr, nullptr, dhh_s, wsm_s, decB, decB0,
        hb0, hb1, cbuf, Hall, flags + 4096);

    z_final<<<dim3(1024, 4), 256, 0, stream>>>(Hall, zw_s, z_b, out);
}